// Round 2
// baseline (904.353 us; speedup 1.0000x reference)
//
#include <hip/hip_runtime.h>
#include <math.h>

#define LSEQ 1024
#define DDIM 256
#define NC 16          // chunks along L
#define CHUNK 64
#define CSTR 116       // packed coef row stride (floats)
#define PI_D 3.14159265358979323846

// coef row layout (per b,l):
// [0:16) cK  [16:32) sK  [32:48) cQ  [48:64) sQ
// [64:68) cJK [68:72) sJK [72:76) cJQ [76:80) sJQ
// [80:96) cP [96:112) sP  [112] gate  [113:116) pad

// ---------------- K1: phases + joint phases + pos phases + V ----------------
__global__ void k_phases(const float* __restrict__ x, const float* __restrict__ kp,
                         const float* __restrict__ qp, const float* __restrict__ vp,
                         const float* __restrict__ pos_freqs,
                         float* __restrict__ coef, float* __restrict__ V) {
    int bl = blockIdx.x;            // b*L + l
    int l  = bl & (LSEQ - 1);
    int t  = threadIdx.x;
    __shared__ float xs[DDIM];
    __shared__ double phi[32];
    xs[t] = x[bl * DDIM + t];
    __syncthreads();
    float* crow = coef + (size_t)bl * CSTR;
    if (t < 32) {
        const float* W = (t < 16) ? kp : qp;
        int j = t & 15;
        double acc = 0.0;
        for (int i = 0; i < DDIM; ++i) acc += (double)xs[i] * (double)W[i * 16 + j];
        double ph = tanh(acc) * PI_D;
        phi[t] = ph;
        double c, s; sincos(ph, &s, &c);  // note: sincos(x, &sin, &cos)
        int base = (t < 16) ? 0 : 32;
        crow[base + j] = (float)c;
        crow[base + 16 + j] = (float)s;
    }
    __syncthreads();
    if (t < 8) {    // joint phases: sum over 4 sets at fixed pp
        int p = t & 3;
        const double* p4 = phi + ((t < 4) ? 0 : 16);
        double sum = p4[p] + p4[4 + p] + p4[8 + p] + p4[12 + p];
        double c, s; sincos(sum, &s, &c);
        int base = (t < 4) ? 64 : 72;
        crow[base + p] = (float)c;
        crow[base + 4 + p] = (float)s;
    }
    if (t >= 32 && t < 48) {  // positional phases
        int pl = t - 32;
        // match f32 association: ((l * pf) * 2) * pi, but compute transcendental in f64
        float arg32 = (((float)l * pos_freqs[pl]) * 2.0f) * 3.14159265358979323846f;
        double c, s; sincos((double)arg32, &s, &c);
        crow[80 + pl] = (float)c;
        crow[96 + pl] = (float)s;
    }
    // V = x @ value_proj (one output column per thread)
    double acc = 0.0;
    for (int i = 0; i < DDIM; ++i) acc += (double)xs[i] * (double)vp[i * DDIM + t];
    V[(size_t)bl * DDIM + t] = (float)acc;
}

// ---------------- K2: running mean / std along L ----------------
__global__ void k_stats(const float* __restrict__ x, float* __restrict__ rmean,
                        float* __restrict__ rstd) {
    int b = blockIdx.x, d = threadIdx.x;
    double cs = 0.0, css = 0.0;
    for (int l = 0; l < LSEQ; ++l) {
        size_t idx = ((size_t)(b * LSEQ + l)) * DDIM + d;
        double v = (double)x[idx];
        cs += v; css += v * v;
        double inv = 1.0 / (double)(l + 1);
        double m = cs * inv;
        double var = css * inv - m * m;
        rmean[idx] = (float)m;
        rstd[idx] = (float)sqrt(fmax(var, 1e-8));
    }
}

// ---------------- K3: LTM phases + persistent readout ----------------
__global__ void k_ltm(const float* __restrict__ x, const float* __restrict__ rmean,
                      const float* __restrict__ rstd, const float* __restrict__ lkp,
                      const float* __restrict__ bre, const float* __restrict__ bim,
                      float* __restrict__ pers) {
    int bl = blockIdx.x, t = threadIdx.x;
    __shared__ float ins[768];
    __shared__ float cs_[16], sn_[16];
    size_t row = (size_t)bl * DDIM;
    ins[t]        = x[row + t];
    ins[256 + t]  = rmean[row + t];
    ins[512 + t]  = rstd[row + t];
    __syncthreads();
    if (t < 16) {
        double acc = 0.0;
        for (int i = 0; i < 768; ++i) acc += (double)ins[i] * (double)lkp[i * 16 + t];
        double th = tanh(acc) * PI_D;
        double c, s; sincos(th, &s, &c);
        cs_[t] = (float)c; sn_[t] = (float)s;
    }
    __syncthreads();
    double acc = 0.0;
    #pragma unroll
    for (int pl = 0; pl < 16; ++pl)
        acc += (double)bre[pl * DDIM + t] * (double)cs_[pl]
             + (double)bim[pl * DDIM + t] * (double)sn_[pl];
    pers[row + t] = (float)acc;
}

// ---------------- K4: write gate (exclusive cumsum of joint_key) ----------------
__global__ void k_gate(float* __restrict__ coef) {
    __shared__ float jk[LSEQ][8];   // cJK[0:4], sJK[4:8]
    __shared__ float mag[LSEQ][4];
    int t = threadIdx.x;
    for (int b = 0; b < 2; ++b) {
        for (int idx = t; idx < LSEQ * 8; idx += 256) {
            int l = idx >> 3, k = idx & 7;
            jk[l][k] = coef[((size_t)(b * LSEQ + l)) * CSTR + 64 + k];
        }
        __syncthreads();
        if (t < 4) {
            int p = t;
            double ar = 0.0, ai = 0.0;
            for (int l = 0; l < LSEQ; ++l) {
                mag[l][p] = (float)sqrt(ar * ar + ai * ai);  // exclusive
                ar += (double)jk[l][p]; ai += (double)jk[l][4 + p];
            }
        }
        __syncthreads();
        for (int l = t; l < LSEQ; l += 256) {
            double m = 0.25 * ((double)mag[l][0] + (double)mag[l][1]
                             + (double)mag[l][2] + (double)mag[l][3]);
            double nr = m / sqrt(fmax((double)l, 1.0));
            double sup = 0.5 * (1.0 - tanh(5.0 * (nr - 0.3)));
            double g = 1.0 / (1.0 + exp(-5.0 * (sup - 0.5)));
            coef[((size_t)(b * LSEQ + l)) * CSTR + 112] = (float)g;
        }
        __syncthreads();
    }
}

// ---------------- K5a: per-chunk plane sums ----------------
__global__ void k_chunksum(const float* __restrict__ coef, const float* __restrict__ V,
                           float* __restrict__ S) {
    int c = blockIdx.x, b = blockIdx.y, d = threadIdx.x;
    double sre[36], sim[36];
    #pragma unroll
    for (int i = 0; i < 36; ++i) { sre[i] = 0.0; sim[i] = 0.0; }
    for (int l = c * CHUNK; l < c * CHUNK + CHUNK; ++l) {
        const float* crow = coef + ((size_t)(b * LSEQ + l)) * CSTR;
        double g = (double)crow[112];
        double v = (double)V[((size_t)(b * LSEQ + l)) * DDIM + d];
        double vg = v * g;
        #pragma unroll
        for (int i = 0; i < 16; ++i) { sre[i] += (double)crow[i] * vg; sim[i] += (double)crow[16 + i] * vg; }
        #pragma unroll
        for (int i = 0; i < 4; ++i)  { sre[16+i] += (double)crow[64+i] * vg; sim[16+i] += (double)crow[68+i] * vg; }
        #pragma unroll
        for (int i = 0; i < 16; ++i) { sre[20+i] += (double)crow[80+i] * v;  sim[20+i] += (double)crow[96+i] * v; }
    }
    size_t base = ((size_t)(b * NC + c) * 72) * DDIM + d;
    #pragma unroll
    for (int i = 0; i < 36; ++i) {
        S[base + (size_t)i * DDIM] = (float)sre[i];
        S[base + (size_t)(36 + i) * DDIM] = (float)sim[i];
    }
}

// ---------------- K5b: exclusive prefix over chunks ----------------
__global__ void k_prefix(const float* __restrict__ S, float* __restrict__ P) {
    int q = blockIdx.x, b = blockIdx.y, d = threadIdx.x;
    double acc = 0.0;
    for (int c = 0; c < NC; ++c) {
        size_t idx = ((size_t)(b * NC + c) * 72 + q) * DDIM + d;
        P[idx] = (float)acc;
        acc += (double)S[idx];
    }
}

// ---------------- K5c: within-chunk inclusive scan + retrieval ----------------
__global__ void k_scan(const float* __restrict__ coef, const float* __restrict__ V,
                       const float* __restrict__ P, float* __restrict__ tcp) {
    int c = blockIdx.x, b = blockIdx.y, d = threadIdx.x;
    double sre[36], sim[36];
    size_t base = ((size_t)(b * NC + c) * 72) * DDIM + d;
    #pragma unroll
    for (int i = 0; i < 36; ++i) {
        sre[i] = (double)P[base + (size_t)i * DDIM];
        sim[i] = (double)P[base + (size_t)(36 + i) * DDIM];
    }
    for (int l = c * CHUNK; l < c * CHUNK + CHUNK; ++l) {
        const float* crow = coef + ((size_t)(b * LSEQ + l)) * CSTR;
        double g = (double)crow[112];
        double v = (double)V[((size_t)(b * LSEQ + l)) * DDIM + d];
        double vg = v * g;
        double rb = 0.0, rc = 0.0, rp = 0.0;
        #pragma unroll
        for (int i = 0; i < 16; ++i) {
            sre[i] += (double)crow[i] * vg;       sim[i] += (double)crow[16 + i] * vg;
            rb += (double)crow[32 + i] * sre[i] + (double)crow[48 + i] * sim[i];
        }
        #pragma unroll
        for (int i = 0; i < 4; ++i) {
            sre[16+i] += (double)crow[64+i] * vg; sim[16+i] += (double)crow[68+i] * vg;
            rc += (double)crow[72+i] * sre[16+i] + (double)crow[76+i] * sim[16+i];
        }
        #pragma unroll
        for (int i = 0; i < 16; ++i) {
            sre[20+i] += (double)crow[80+i] * v;  sim[20+i] += (double)crow[96+i] * v;
            rp += (double)crow[80+i] * sre[20+i] + (double)crow[96+i] * sim[20+i];
        }
        tcp[((size_t)(b * LSEQ + l)) * DDIM + d] =
            (float)(0.1 * (0.25 * rb + rc) + 0.5 * rp);
    }
}

// ---------------- K6: epilogue: (total/norm) @ out_proj + x ----------------
__global__ void k_out(const float* __restrict__ x, const float* __restrict__ tcp,
                      const float* __restrict__ pers, const float* __restrict__ op,
                      float* __restrict__ out) {
    int bl = blockIdx.x, t = threadIdx.x;
    int l = bl & (LSEQ - 1);
    __shared__ float ts[DDIM];
    size_t row = (size_t)bl * DDIM;
    double invn = 1.0 / (2.0 * sqrt((double)(l + 1)));
    ts[t] = (float)(((double)tcp[row + t] + 0.125 * (double)pers[row + t]) * invn);
    __syncthreads();
    double acc = 0.0;
    for (int i = 0; i < DDIM; ++i) acc += (double)ts[i] * (double)op[i * DDIM + t];
    out[row + t] = (float)((double)x[row + t] + acc);
}

extern "C" void kernel_launch(void* const* d_in, const int* in_sizes, int n_in,
                              void* d_out, int out_size, void* d_ws, size_t ws_size,
                              hipStream_t stream) {
    const float* x   = (const float*)d_in[0];
    const float* kp  = (const float*)d_in[1];
    const float* qp  = (const float*)d_in[2];
    const float* vp  = (const float*)d_in[3];
    const float* op  = (const float*)d_in[4];
    const float* lkp = (const float*)d_in[5];
    const float* pf  = (const float*)d_in[7];
    const float* bre = (const float*)d_in[10];
    const float* bim = (const float*)d_in[11];
    float* out = (float*)d_out;

    const int B = 2;
    float* w = (float*)d_ws;
    size_t off = 0;
    float* coef  = w + off; off += (size_t)B * LSEQ * CSTR;
    float* V     = w + off; off += (size_t)B * LSEQ * DDIM;
    float* rmean = w + off; off += (size_t)B * LSEQ * DDIM;
    float* rstd  = w + off; off += (size_t)B * LSEQ * DDIM;
    float* pers  = w + off; off += (size_t)B * LSEQ * DDIM;
    float* tcp   = w + off; off += (size_t)B * LSEQ * DDIM;
    float* S     = w + off; off += (size_t)B * NC * 72 * DDIM;
    float* P     = w + off; off += (size_t)B * NC * 72 * DDIM;

    dim3 blk(DDIM);
    k_phases<<<dim3(B * LSEQ), blk, 0, stream>>>(x, kp, qp, vp, pf, coef, V);
    k_stats<<<dim3(B), blk, 0, stream>>>(x, rmean, rstd);
    k_ltm<<<dim3(B * LSEQ), blk, 0, stream>>>(x, rmean, rstd, lkp, bre, bim, pers);
    k_gate<<<dim3(1), blk, 0, stream>>>(coef);
    k_chunksum<<<dim3(NC, B), blk, 0, stream>>>(coef, V, S);
    k_prefix<<<dim3(72, B), blk, 0, stream>>>(S, P);
    k_scan<<<dim3(NC, B), blk, 0, stream>>>(coef, V, P, tcp);
    k_out<<<dim3(B * LSEQ), blk, 0, stream>>>(x, tcp, pers, op, out);
}

// Round 3
// 452.570 us; speedup vs baseline: 1.9983x; 1.9983x over previous
//
#include <hip/hip_runtime.h>
#include <math.h>

#define LSEQ 1024
#define DDIM 256
#define NC 32          // chunks along L
#define CHUNK 32
#define CSTR 144       // packed coef row stride (floats)
#define PI_F 3.14159265358979323846f

// coef row layout (per b,l), 36 planes = 16 bank + 4 joint + 16 pos:
// [0:36)    Kre  (bank/joint gated later by k_gate; pos ungated)
// [36:72)   Kim
// [72:108)  Qre  (retrieval weights folded: bank 0.025, joint 0.1, pos 0.5)
// [108:144) Qim

// ---------------- K1: phases + joint phases + pos phases + V ----------------
__global__ void k_phases(const float* __restrict__ x, const float* __restrict__ kp,
                         const float* __restrict__ qp, const float* __restrict__ vp,
                         const float* __restrict__ pos_freqs,
                         float* __restrict__ coef, float* __restrict__ V) {
    int bl = blockIdx.x;            // b*L + l
    int l  = bl & (LSEQ - 1);
    int t  = threadIdx.x;
    __shared__ float xs[DDIM];
    __shared__ float phi[32];
    xs[t] = x[bl * DDIM + t];
    __syncthreads();
    float* crow = coef + (size_t)bl * CSTR;
    if (t < 32) {
        const float* W = (t < 16) ? kp : qp;
        int j = t & 15;
        float acc = 0.f;
        #pragma unroll 8
        for (int i = 0; i < DDIM; ++i) acc += xs[i] * W[i * 16 + j];
        float ph = tanhf(acc) * PI_F;
        phi[t] = ph;
        float s, c; sincosf(ph, &s, &c);   // SIN FIRST
        if (t < 16) { crow[j] = c;              crow[36 + j] = s; }
        else        { crow[72 + j] = 0.025f * c; crow[108 + j] = 0.025f * s; }
    }
    __syncthreads();
    if (t < 8) {    // joint phases: sum over 4 sets at fixed pp (flat j = s*4+p)
        int p = t & 3;
        const float* p4 = phi + ((t < 4) ? 0 : 16);
        float sum = p4[p] + p4[4 + p] + p4[8 + p] + p4[12 + p];
        float s, c; sincosf(sum, &s, &c);
        if (t < 4) { crow[16 + p] = c;          crow[52 + p] = s; }
        else       { crow[88 + p] = 0.1f * c;   crow[124 + p] = 0.1f * s; }
    }
    if (t >= 32 && t < 48) {  // positional phases (key AND weighted query copies)
        int pl = t - 32;
        float a = (((float)l * pos_freqs[pl]) * 2.0f) * PI_F;
        float s, c; sincosf(a, &s, &c);
        crow[20 + pl] = c;          crow[56 + pl] = s;
        crow[92 + pl] = 0.5f * c;   crow[128 + pl] = 0.5f * s;
    }
    // V = x @ value_proj (one output column per thread)
    float acc = 0.f;
    #pragma unroll 8
    for (int i = 0; i < DDIM; ++i) acc += xs[i] * vp[i * DDIM + t];
    V[(size_t)bl * DDIM + t] = acc;
}

// ---------------- K2: running mean / std along L ----------------
__global__ void k_stats(const float* __restrict__ x, float* __restrict__ rmean,
                        float* __restrict__ rstd) {
    int b = blockIdx.x, d = threadIdx.x;
    float cs = 0.f, css = 0.f;
    #pragma unroll 4
    for (int l = 0; l < LSEQ; ++l) {
        size_t idx = ((size_t)(b * LSEQ + l)) * DDIM + d;
        float v = x[idx];
        cs += v; css += v * v;
        float inv = 1.0f / (float)(l + 1);
        float m = cs * inv;
        float var = css * inv - m * m;
        rmean[idx] = m;
        rstd[idx] = sqrtf(fmaxf(var, 1e-8f));
    }
}

// ---------------- K3: LTM phases + persistent readout ----------------
__global__ void k_ltm(const float* __restrict__ x, const float* __restrict__ rmean,
                      const float* __restrict__ rstd, const float* __restrict__ lkp,
                      const float* __restrict__ bre, const float* __restrict__ bim,
                      float* __restrict__ pers) {
    int bl = blockIdx.x, t = threadIdx.x;
    __shared__ float ins[768];
    __shared__ float part[16][17];
    __shared__ float cs_[16], sn_[16];
    size_t row = (size_t)bl * DDIM;
    ins[t]        = x[row + t];
    ins[256 + t]  = rmean[row + t];
    ins[512 + t]  = rstd[row + t];
    __syncthreads();
    {   // parallel 768-dot: 16 outputs x 16 groups of 48
        int j = t & 15, g = t >> 4;
        int i0 = g * 48;
        float acc = 0.f;
        #pragma unroll
        for (int i = 0; i < 48; ++i) acc += ins[i0 + i] * lkp[(i0 + i) * 16 + j];
        part[g][j] = acc;
    }
    __syncthreads();
    if (t < 16) {
        float acc = 0.f;
        #pragma unroll
        for (int g = 0; g < 16; ++g) acc += part[g][t];
        float th = tanhf(acc) * PI_F;
        float s, c; sincosf(th, &s, &c);   // SIN FIRST
        cs_[t] = c; sn_[t] = s;
    }
    __syncthreads();
    float acc = 0.f;
    #pragma unroll
    for (int pl = 0; pl < 16; ++pl)
        acc += bre[pl * DDIM + t] * cs_[pl] + bim[pl * DDIM + t] * sn_[pl];
    pers[row + t] = acc;   // raw persistent sum; weighted 0.125 in k_scan
}

// ---------------- K4: write gate + fold gate into key coefs ----------------
__global__ void k_gate(float* __restrict__ coef) {
    __shared__ float jk[LSEQ][8];   // joint key re[0:4] im[4:8]; re slots reused for mags
    __shared__ float gs[LSEQ];
    int t = threadIdx.x;
    for (int b = 0; b < 2; ++b) {
        for (int idx = t; idx < LSEQ * 8; idx += 256) {
            int l = idx >> 3, k = idx & 7;
            jk[l][k] = coef[((size_t)(b * LSEQ + l)) * CSTR + ((k < 4) ? (16 + k) : (48 + k))];
        }
        __syncthreads();
        if (t < 4) {   // serial exclusive-cumsum magnitude per joint plane
            int p = t;
            float ar = 0.f, ai = 0.f;
            for (int l = 0; l < LSEQ; ++l) {
                float re = jk[l][p], im = jk[l][4 + p];
                jk[l][p] = sqrtf(ar * ar + ai * ai);  // exclusive mag, in place
                ar += re; ai += im;
            }
        }
        __syncthreads();
        for (int l = t; l < LSEQ; l += 256) {
            float m = 0.25f * (jk[l][0] + jk[l][1] + jk[l][2] + jk[l][3]);
            float nr = m / sqrtf(fmaxf((float)l, 1.0f));
            float sup = 0.5f * (1.0f - tanhf(5.0f * (nr - 0.3f)));
            gs[l] = 1.0f / (1.0f + expf(-5.0f * (sup - 0.5f)));
        }
        __syncthreads();
        // scale gated key slots: Kre[0:20) at [0:20), Kim[0:20) at [36:56)
        for (int idx = t; idx < LSEQ * 40; idx += 256) {
            int l = idx / 40, i = idx % 40;
            int off = (i < 20) ? i : (16 + i);
            coef[((size_t)(b * LSEQ + l)) * CSTR + off] *= gs[l];
        }
        __syncthreads();
    }
}

// ---------------- K5a: per-chunk plane sums ----------------
__global__ void k_chunksum(const float* __restrict__ coef, const float* __restrict__ V,
                           float* __restrict__ S) {
    int c = blockIdx.x, b = blockIdx.y, d = threadIdx.x;
    __shared__ __align__(16) float ct[CHUNK][CSTR];
    {   // flat float4 memcpy of the chunk's coef rows
        const float4* src = (const float4*)(coef + ((size_t)(b * LSEQ + c * CHUNK)) * CSTR);
        float4* dst = (float4*)&ct[0][0];
        for (int idx = threadIdx.x; idx < CHUNK * CSTR / 4; idx += 256) dst[idx] = src[idx];
    }
    float vbuf[CHUNK];
    #pragma unroll
    for (int l = 0; l < CHUNK; ++l)
        vbuf[l] = V[((size_t)(b * LSEQ + c * CHUNK + l)) * DDIM + d];
    __syncthreads();
    float sre[36], sim[36];
    #pragma unroll
    for (int i = 0; i < 36; ++i) { sre[i] = 0.f; sim[i] = 0.f; }
    for (int l = 0; l < CHUNK; ++l) {
        float v = vbuf[l];
        const float4* k4 = (const float4*)&ct[l][0];
        #pragma unroll
        for (int q = 0; q < 9; ++q) {
            float4 kr = k4[q], ki = k4[9 + q];
            sre[4*q+0] += kr.x * v; sre[4*q+1] += kr.y * v;
            sre[4*q+2] += kr.z * v; sre[4*q+3] += kr.w * v;
            sim[4*q+0] += ki.x * v; sim[4*q+1] += ki.y * v;
            sim[4*q+2] += ki.z * v; sim[4*q+3] += ki.w * v;
        }
    }
    size_t base = ((size_t)(b * NC + c) * 72) * DDIM + d;
    #pragma unroll
    for (int i = 0; i < 36; ++i) {
        S[base + (size_t)i * DDIM] = sre[i];
        S[base + (size_t)(36 + i) * DDIM] = sim[i];
    }
}

// ---------------- K5b: exclusive prefix over chunks (in place) ----------------
__global__ void k_prefix(float* __restrict__ S) {
    int q = blockIdx.x, b = blockIdx.y, d = threadIdx.x;
    float acc = 0.f;
    for (int c = 0; c < NC; ++c) {
        size_t idx = ((size_t)(b * NC + c) * 72 + q) * DDIM + d;
        float tmp = S[idx];
        S[idx] = acc;
        acc += tmp;
    }
}

// ---------------- K5c: within-chunk scan + retrieval (+0.125*pers, in place) ----------------
__global__ void k_scan(const float* __restrict__ coef, const float* __restrict__ V,
                       const float* __restrict__ S, float* __restrict__ tp) {
    int c = blockIdx.x, b = blockIdx.y, d = threadIdx.x;
    __shared__ __align__(16) float ct[CHUNK][CSTR];
    {
        const float4* src = (const float4*)(coef + ((size_t)(b * LSEQ + c * CHUNK)) * CSTR);
        float4* dst = (float4*)&ct[0][0];
        for (int idx = threadIdx.x; idx < CHUNK * CSTR / 4; idx += 256) dst[idx] = src[idx];
    }
    float vbuf[CHUNK];
    #pragma unroll
    for (int l = 0; l < CHUNK; ++l)
        vbuf[l] = V[((size_t)(b * LSEQ + c * CHUNK + l)) * DDIM + d];
    float sre[36], sim[36];
    size_t base = ((size_t)(b * NC + c) * 72) * DDIM + d;
    #pragma unroll
    for (int i = 0; i < 36; ++i) {
        sre[i] = S[base + (size_t)i * DDIM];
        sim[i] = S[base + (size_t)(36 + i) * DDIM];
    }
    __syncthreads();
    for (int l = 0; l < CHUNK; ++l) {
        float v = vbuf[l];
        const float4* r4 = (const float4*)&ct[l][0];
        float rx = 0.f, ry = 0.f, rz = 0.f, rw = 0.f;   // 4 chains to break dep
        #pragma unroll
        for (int q = 0; q < 9; ++q) {
            float4 kr = r4[q], ki = r4[9 + q], qr = r4[18 + q], qi = r4[27 + q];
            sre[4*q+0] += kr.x * v; rx += qr.x * sre[4*q+0];
            sre[4*q+1] += kr.y * v; ry += qr.y * sre[4*q+1];
            sre[4*q+2] += kr.z * v; rz += qr.z * sre[4*q+2];
            sre[4*q+3] += kr.w * v; rw += qr.w * sre[4*q+3];
            sim[4*q+0] += ki.x * v; rx += qi.x * sim[4*q+0];
            sim[4*q+1] += ki.y * v; ry += qi.y * sim[4*q+1];
            sim[4*q+2] += ki.z * v; rz += qi.z * sim[4*q+2];
            sim[4*q+3] += ki.w * v; rw += qi.w * sim[4*q+3];
        }
        size_t oidx = ((size_t)(b * LSEQ + c * CHUNK + l)) * DDIM + d;
        tp[oidx] = ((rx + ry) + (rz + rw)) + 0.125f * tp[oidx];  // tp aliases pers
    }
}

// ---------------- K6: epilogue: (total/norm) @ out_proj + x ----------------
__global__ void k_out(const float* __restrict__ x, const float* __restrict__ tp,
                      const float* __restrict__ op, float* __restrict__ out) {
    int bl = blockIdx.x, t = threadIdx.x;
    int l = bl & (LSEQ - 1);
    __shared__ __align__(16) float ts[DDIM];
    size_t row = (size_t)bl * DDIM;
    float invn = 1.0f / (2.0f * sqrtf((float)(l + 1)));
    ts[t] = tp[row + t] * invn;
    __syncthreads();
    float a0 = 0.f, a1 = 0.f, a2 = 0.f, a3 = 0.f;
    const float4* t4 = (const float4*)ts;
    #pragma unroll 4
    for (int i = 0; i < DDIM / 4; ++i) {
        float4 v = t4[i];
        a0 += v.x * op[(4*i+0) * DDIM + t];
        a1 += v.y * op[(4*i+1) * DDIM + t];
        a2 += v.z * op[(4*i+2) * DDIM + t];
        a3 += v.w * op[(4*i+3) * DDIM + t];
    }
    out[row + t] = x[row + t] + ((a0 + a1) + (a2 + a3));
}

extern "C" void kernel_launch(void* const* d_in, const int* in_sizes, int n_in,
                              void* d_out, int out_size, void* d_ws, size_t ws_size,
                              hipStream_t stream) {
    const float* x   = (const float*)d_in[0];
    const float* kp  = (const float*)d_in[1];
    const float* qp  = (const float*)d_in[2];
    const float* vp  = (const float*)d_in[3];
    const float* op  = (const float*)d_in[4];
    const float* lkp = (const float*)d_in[5];
    const float* pf  = (const float*)d_in[7];
    const float* bre = (const float*)d_in[10];
    const float* bim = (const float*)d_in[11];
    float* out = (float*)d_out;

    const int B = 2;
    float* w = (float*)d_ws;
    size_t off = 0;
    float* coef  = w + off; off += (size_t)B * LSEQ * CSTR;       // 294912
    float* V     = w + off; off += (size_t)B * LSEQ * DDIM;       // 524288
    float* rmean = w + off; off += (size_t)B * LSEQ * DDIM;
    float* rstd  = w + off; off += (size_t)B * LSEQ * DDIM;
    float* pers  = w + off; off += (size_t)B * LSEQ * DDIM;       // aliased as tcp
    float* S     = w + off; off += (size_t)B * NC * 72 * DDIM;    // 1179648
    // total ~13.6 MB

    dim3 blk(DDIM);
    k_phases<<<dim3(B * LSEQ), blk, 0, stream>>>(x, kp, qp, vp, pf, coef, V);
    k_stats<<<dim3(B), blk, 0, stream>>>(x, rmean, rstd);
    k_ltm<<<dim3(B * LSEQ), blk, 0, stream>>>(x, rmean, rstd, lkp, bre, bim, pers);
    k_gate<<<dim3(1), blk, 0, stream>>>(coef);
    k_chunksum<<<dim3(NC, B), blk, 0, stream>>>(coef, V, S);
    k_prefix<<<dim3(72, B), blk, 0, stream>>>(S);
    k_scan<<<dim3(NC, B), blk, 0, stream>>>(coef, V, S, pers);
    k_out<<<dim3(B * LSEQ), blk, 0, stream>>>(x, pers, op, out);
}

// Round 4
// 166.213 us; speedup vs baseline: 5.4409x; 2.7228x over previous
//
#include <hip/hip_runtime.h>
#include <math.h>

#define LSEQ 1024
#define DDIM 256
#define NC 32          // chunks along L (scan pipeline)
#define CHUNK 32
#define NCS 16         // chunks along L (stats)
#define CHS 64
#define CSTR 144       // packed coef row stride (floats)
#define PI_F 3.14159265358979323846f
#define F(l) ((l) + ((l) >> 5))   // bank-padded LDS index

// coef row layout (per b,l), 36 planes = 16 bank + 4 joint + 16 pos:
// [0:36) Kre  [36:72) Kim  [72:108) Qre  [108:144) Qim
// (Q weights folded: bank 0.025, joint 0.1, pos 0.5. Gate NOT folded.)

// ---------------- K1: phases + joint phases + pos phases + V ----------------
__global__ void k_phases(const float* __restrict__ x, const float* __restrict__ kp,
                         const float* __restrict__ qp, const float* __restrict__ vp,
                         const float* __restrict__ pos_freqs,
                         float* __restrict__ coef, float* __restrict__ V) {
    int bl = blockIdx.x;            // b*L + l
    int l  = bl & (LSEQ - 1);
    int t  = threadIdx.x;
    __shared__ float xs[DDIM];
    __shared__ float phi[32];
    xs[t] = x[bl * DDIM + t];
    __syncthreads();
    float* crow = coef + (size_t)bl * CSTR;
    if (t < 32) {
        const float* W = (t < 16) ? kp : qp;
        int j = t & 15;
        float acc = 0.f;
        #pragma unroll 8
        for (int i = 0; i < DDIM; ++i) acc += xs[i] * W[i * 16 + j];
        float ph = tanhf(acc) * PI_F;
        phi[t] = ph;
        float s, c; sincosf(ph, &s, &c);   // SIN FIRST
        if (t < 16) { crow[j] = c;               crow[36 + j] = s; }
        else        { crow[72 + j] = 0.025f * c; crow[108 + j] = 0.025f * s; }
    }
    __syncthreads();
    if (t < 8) {    // joint phases: sum over 4 sets at fixed pp
        int p = t & 3;
        const float* p4 = phi + ((t < 4) ? 0 : 16);
        float sum = p4[p] + p4[4 + p] + p4[8 + p] + p4[12 + p];
        float s, c; sincosf(sum, &s, &c);
        if (t < 4) { crow[16 + p] = c;          crow[52 + p] = s; }
        else       { crow[88 + p] = 0.1f * c;   crow[124 + p] = 0.1f * s; }
    }
    if (t >= 32 && t < 48) {  // positional phases (key AND weighted query copies)
        int pl = t - 32;
        float a = (((float)l * pos_freqs[pl]) * 2.0f) * PI_F;
        float s, c; sincosf(a, &s, &c);
        crow[20 + pl] = c;          crow[56 + pl] = s;
        crow[92 + pl] = 0.5f * c;   crow[128 + pl] = 0.5f * s;
    }
    // V = x @ value_proj (one output column per thread)
    float acc = 0.f;
    #pragma unroll 8
    for (int i = 0; i < DDIM; ++i) acc += xs[i] * vp[i * DDIM + t];
    V[(size_t)bl * DDIM + t] = acc;
}

// ---------------- K2a: per-chunk sums for running stats ----------------
__global__ void k_stats1(const float* __restrict__ x, float* __restrict__ Ssum,
                         float* __restrict__ Ssq) {
    int c = blockIdx.x, b = blockIdx.y, d = threadIdx.x;
    float s1 = 0.f, s2 = 0.f;
    for (int l = c * CHS; l < c * CHS + CHS; ++l) {
        float v = x[((size_t)(b * LSEQ + l)) * DDIM + d];
        s1 += v; s2 += v * v;
    }
    Ssum[(b * NCS + c) * DDIM + d] = s1;
    Ssq [(b * NCS + c) * DDIM + d] = s2;
}

// ---------------- K2b: running mean / std within chunk ----------------
__global__ void k_stats2(const float* __restrict__ x, const float* __restrict__ Ssum,
                         const float* __restrict__ Ssq, float* __restrict__ rmean,
                         float* __restrict__ rstd) {
    int c = blockIdx.x, b = blockIdx.y, d = threadIdx.x;
    float cs = 0.f, css = 0.f;
    for (int cc = 0; cc < c; ++cc) {
        cs  += Ssum[(b * NCS + cc) * DDIM + d];
        css += Ssq [(b * NCS + cc) * DDIM + d];
    }
    for (int l = c * CHS; l < c * CHS + CHS; ++l) {
        size_t idx = ((size_t)(b * LSEQ + l)) * DDIM + d;
        float v = x[idx];
        cs += v; css += v * v;
        float inv = 1.0f / (float)(l + 1);
        float m = cs * inv;
        float var = css * inv - m * m;
        rmean[idx] = m;
        rstd[idx] = sqrtf(fmaxf(var, 1e-8f));
    }
}

// ---------------- K3: LTM phases + persistent readout ----------------
__global__ void k_ltm(const float* __restrict__ x, const float* __restrict__ rmean,
                      const float* __restrict__ rstd, const float* __restrict__ lkp,
                      const float* __restrict__ bre, const float* __restrict__ bim,
                      float* __restrict__ pers) {
    int bl = blockIdx.x, t = threadIdx.x;
    __shared__ float ins[768];
    __shared__ float part[16][17];
    __shared__ float cs_[16], sn_[16];
    size_t row = (size_t)bl * DDIM;
    ins[t]        = x[row + t];
    ins[256 + t]  = rmean[row + t];
    ins[512 + t]  = rstd[row + t];
    __syncthreads();
    {   // parallel 768-dot: 16 outputs x 16 groups of 48
        int j = t & 15, g = t >> 4;
        int i0 = g * 48;
        float acc = 0.f;
        #pragma unroll
        for (int i = 0; i < 48; ++i) acc += ins[i0 + i] * lkp[(i0 + i) * 16 + j];
        part[g][j] = acc;
    }
    __syncthreads();
    if (t < 16) {
        float acc = 0.f;
        #pragma unroll
        for (int g = 0; g < 16; ++g) acc += part[g][t];
        float th = tanhf(acc) * PI_F;
        float s, c; sincosf(th, &s, &c);   // SIN FIRST
        cs_[t] = c; sn_[t] = s;
    }
    __syncthreads();
    float acc = 0.f;
    #pragma unroll
    for (int pl = 0; pl < 16; ++pl)
        acc += bre[pl * DDIM + t] * cs_[pl] + bim[pl * DDIM + t] * sn_[pl];
    pers[row + t] = acc;   // raw persistent sum; weighted 0.125 in k_scan
}

// ---------------- K4: write gate via parallel prefix scan ----------------
__global__ void k_gate(const float* __restrict__ coef, float* __restrict__ gate) {
    int b = blockIdx.x, t = threadIdx.x;
    __shared__ float sm[8][1056];   // 8 channels, padded
    __shared__ float part[8][33];
    for (int idx = t; idx < LSEQ * 8; idx += 256) {
        int l = idx >> 3, k = idx & 7;
        sm[k][F(l)] = coef[((size_t)(b * LSEQ + l)) * CSTR + ((k < 4) ? (16 + k) : (48 + k))];
    }
    __syncthreads();
    int g = t >> 5, r = t & 31;
    {   // local sums of 32-element segments
        float s = 0.f;
        int base = r * 33;    // F(r*32+i) = r*33+i
        #pragma unroll
        for (int i = 0; i < 32; ++i) s += sm[g][base + i];
        part[g][r] = s;
    }
    __syncthreads();
    if (r == 0) {   // exclusive scan of 32 partials per channel
        float run = 0.f;
        #pragma unroll
        for (int i = 0; i < 32; ++i) { float tmp = part[g][i]; part[g][i] = run; run += tmp; }
    }
    __syncthreads();
    {   // replay: replace with exclusive prefix
        float run = part[g][r];
        int base = r * 33;
        #pragma unroll
        for (int i = 0; i < 32; ++i) {
            float tmp = sm[g][base + i];
            sm[g][base + i] = run;
            run += tmp;
        }
    }
    __syncthreads();
    for (int l = t; l < LSEQ; l += 256) {
        float m = 0.f;
        int fl = F(l);
        #pragma unroll
        for (int p = 0; p < 4; ++p) {
            float ar = sm[p][fl], ai = sm[4 + p][fl];
            m += sqrtf(ar * ar + ai * ai);
        }
        m *= 0.25f;
        float nr = m / sqrtf(fmaxf((float)l, 1.0f));
        float sup = 0.5f * (1.0f - tanhf(5.0f * (nr - 0.3f)));
        gate[b * LSEQ + l] = 1.0f / (1.0f + expf(-5.0f * (sup - 0.5f)));
    }
}

// ---------------- K5a: per-chunk plane sums ----------------
__global__ void k_chunksum(const float* __restrict__ coef, const float* __restrict__ V,
                           const float* __restrict__ gate, float* __restrict__ S) {
    int c = blockIdx.x, b = blockIdx.y, d = threadIdx.x;
    __shared__ __align__(16) float ct[CHUNK][CSTR];
    __shared__ float gl[CHUNK];
    {
        const float4* src = (const float4*)(coef + ((size_t)(b * LSEQ + c * CHUNK)) * CSTR);
        float4* dst = (float4*)&ct[0][0];
        for (int idx = threadIdx.x; idx < CHUNK * CSTR / 4; idx += 256) dst[idx] = src[idx];
    }
    if (threadIdx.x < CHUNK) gl[threadIdx.x] = gate[b * LSEQ + c * CHUNK + threadIdx.x];
    float vbuf[CHUNK];
    #pragma unroll
    for (int l = 0; l < CHUNK; ++l)
        vbuf[l] = V[((size_t)(b * LSEQ + c * CHUNK + l)) * DDIM + d];
    __syncthreads();
    float sre[36], sim[36];
    #pragma unroll
    for (int i = 0; i < 36; ++i) { sre[i] = 0.f; sim[i] = 0.f; }
    for (int l = 0; l < CHUNK; ++l) {
        float v = vbuf[l];
        float vg = v * gl[l];
        const float4* k4 = (const float4*)&ct[l][0];
        #pragma unroll
        for (int q = 0; q < 9; ++q) {
            float val = (q <= 4) ? vg : v;   // planes 0-19 gated, 20-35 ungated
            float4 kr = k4[q], ki = k4[9 + q];
            sre[4*q+0] += kr.x * val; sre[4*q+1] += kr.y * val;
            sre[4*q+2] += kr.z * val; sre[4*q+3] += kr.w * val;
            sim[4*q+0] += ki.x * val; sim[4*q+1] += ki.y * val;
            sim[4*q+2] += ki.z * val; sim[4*q+3] += ki.w * val;
        }
    }
    size_t base = ((size_t)(b * NC + c) * 72) * DDIM + d;
    #pragma unroll
    for (int i = 0; i < 36; ++i) {
        S[base + (size_t)i * DDIM] = sre[i];
        S[base + (size_t)(36 + i) * DDIM] = sim[i];
    }
}

// ---------------- K5b: exclusive prefix over chunks (in place) ----------------
__global__ void k_prefix(float* __restrict__ S) {
    int q = blockIdx.x, b = blockIdx.y, d = threadIdx.x;
    float acc = 0.f;
    for (int c = 0; c < NC; ++c) {
        size_t idx = ((size_t)(b * NC + c) * 72 + q) * DDIM + d;
        float tmp = S[idx];
        S[idx] = acc;
        acc += tmp;
    }
}

// ---------------- K5c: within-chunk scan + retrieval (+0.125*pers, in place) ----------------
__global__ void k_scan(const float* __restrict__ coef, const float* __restrict__ V,
                       const float* __restrict__ gate, const float* __restrict__ S,
                       float* __restrict__ tp) {
    int c = blockIdx.x, b = blockIdx.y, d = threadIdx.x;
    __shared__ __align__(16) float ct[CHUNK][CSTR];
    __shared__ float gl[CHUNK];
    {
        const float4* src = (const float4*)(coef + ((size_t)(b * LSEQ + c * CHUNK)) * CSTR);
        float4* dst = (float4*)&ct[0][0];
        for (int idx = threadIdx.x; idx < CHUNK * CSTR / 4; idx += 256) dst[idx] = src[idx];
    }
    if (threadIdx.x < CHUNK) gl[threadIdx.x] = gate[b * LSEQ + c * CHUNK + threadIdx.x];
    float vbuf[CHUNK];
    #pragma unroll
    for (int l = 0; l < CHUNK; ++l)
        vbuf[l] = V[((size_t)(b * LSEQ + c * CHUNK + l)) * DDIM + d];
    float sre[36], sim[36];
    size_t base = ((size_t)(b * NC + c) * 72) * DDIM + d;
    #pragma unroll
    for (int i = 0; i < 36; ++i) {
        sre[i] = S[base + (size_t)i * DDIM];
        sim[i] = S[base + (size_t)(36 + i) * DDIM];
    }
    __syncthreads();
    for (int l = 0; l < CHUNK; ++l) {
        float v = vbuf[l];
        float vg = v * gl[l];
        const float4* r4 = (const float4*)&ct[l][0];
        float rx = 0.f, ry = 0.f, rz = 0.f, rw = 0.f;
        #pragma unroll
        for (int q = 0; q < 9; ++q) {
            float val = (q <= 4) ? vg : v;
            float4 kr = r4[q], ki = r4[9 + q], qr = r4[18 + q], qi = r4[27 + q];
            sre[4*q+0] += kr.x * val; rx += qr.x * sre[4*q+0];
            sre[4*q+1] += kr.y * val; ry += qr.y * sre[4*q+1];
            sre[4*q+2] += kr.z * val; rz += qr.z * sre[4*q+2];
            sre[4*q+3] += kr.w * val; rw += qr.w * sre[4*q+3];
            sim[4*q+0] += ki.x * val; rx += qi.x * sim[4*q+0];
            sim[4*q+1] += ki.y * val; ry += qi.y * sim[4*q+1];
            sim[4*q+2] += ki.z * val; rz += qi.z * sim[4*q+2];
            sim[4*q+3] += ki.w * val; rw += qi.w * sim[4*q+3];
        }
        size_t oidx = ((size_t)(b * LSEQ + c * CHUNK + l)) * DDIM + d;
        tp[oidx] = ((rx + ry) + (rz + rw)) + 0.125f * tp[oidx];  // tp aliases pers
    }
}

// ---------------- K6: epilogue: (total/norm) @ out_proj + x ----------------
__global__ void k_out(const float* __restrict__ x, const float* __restrict__ tp,
                      const float* __restrict__ op, float* __restrict__ out) {
    int bl = blockIdx.x, t = threadIdx.x;
    int l = bl & (LSEQ - 1);
    __shared__ __align__(16) float ts[DDIM];
    size_t row = (size_t)bl * DDIM;
    float invn = 1.0f / (2.0f * sqrtf((float)(l + 1)));
    ts[t] = tp[row + t] * invn;
    __syncthreads();
    float a0 = 0.f, a1 = 0.f, a2 = 0.f, a3 = 0.f;
    const float4* t4 = (const float4*)ts;
    #pragma unroll 4
    for (int i = 0; i < DDIM / 4; ++i) {
        float4 v = t4[i];
        a0 += v.x * op[(4*i+0) * DDIM + t];
        a1 += v.y * op[(4*i+1) * DDIM + t];
        a2 += v.z * op[(4*i+2) * DDIM + t];
        a3 += v.w * op[(4*i+3) * DDIM + t];
    }
    out[row + t] = x[row + t] + ((a0 + a1) + (a2 + a3));
}

extern "C" void kernel_launch(void* const* d_in, const int* in_sizes, int n_in,
                              void* d_out, int out_size, void* d_ws, size_t ws_size,
                              hipStream_t stream) {
    const float* x   = (const float*)d_in[0];
    const float* kp  = (const float*)d_in[1];
    const float* qp  = (const float*)d_in[2];
    const float* vp  = (const float*)d_in[3];
    const float* op  = (const float*)d_in[4];
    const float* lkp = (const float*)d_in[5];
    const float* pf  = (const float*)d_in[7];
    const float* bre = (const float*)d_in[10];
    const float* bim = (const float*)d_in[11];
    float* out = (float*)d_out;

    const int B = 2;
    float* w = (float*)d_ws;
    size_t off = 0;
    float* coef  = w + off; off += (size_t)B * LSEQ * CSTR;       // 294912
    float* V     = w + off; off += (size_t)B * LSEQ * DDIM;       // 524288
    float* rmean = w + off; off += (size_t)B * LSEQ * DDIM;
    float* rstd  = w + off; off += (size_t)B * LSEQ * DDIM;
    float* pers  = w + off; off += (size_t)B * LSEQ * DDIM;       // aliased as tcp
    float* S     = w + off; off += (size_t)B * NC * 72 * DDIM;    // 1179648
    float* gate  = w + off; off += (size_t)B * LSEQ;
    float* Ssum  = w + off; off += (size_t)B * NCS * DDIM;
    float* Ssq   = w + off; off += (size_t)B * NCS * DDIM;
    // total ~14.4 MB

    dim3 blk(DDIM);
    k_phases<<<dim3(B * LSEQ), blk, 0, stream>>>(x, kp, qp, vp, pf, coef, V);
    k_gate<<<dim3(B), blk, 0, stream>>>(coef, gate);
    k_stats1<<<dim3(NCS, B), blk, 0, stream>>>(x, Ssum, Ssq);
    k_stats2<<<dim3(NCS, B), blk, 0, stream>>>(x, Ssum, Ssq, rmean, rstd);
    k_ltm<<<dim3(B * LSEQ), blk, 0, stream>>>(x, rmean, rstd, lkp, bre, bim, pers);
    k_chunksum<<<dim3(NC, B), blk, 0, stream>>>(coef, V, gate, S);
    k_prefix<<<dim3(72, B), blk, 0, stream>>>(S);
    k_scan<<<dim3(NC, B), blk, 0, stream>>>(coef, V, gate, S, pers);
    k_out<<<dim3(B * LSEQ), blk, 0, stream>>>(x, pers, op, out);
}

// Round 5
// 123.645 us; speedup vs baseline: 7.3141x; 1.3443x over previous
//
#include <hip/hip_runtime.h>
#include <math.h>

#define LSEQ 1024
#define DDIM 256
#define NC 64          // chunks along L (scan pipeline)
#define CHUNK 16
#define NCS 16         // chunks along L (stats)
#define CHS 64
#define CSTR 144       // packed coef row stride (floats)
#define PI_F 3.14159265358979323846f
#define F(l) ((l) + ((l) >> 5))   // bank-padded LDS index

// coef row layout (per b,l), 36 planes = 16 bank + 4 joint + 16 pos:
// [0:36) Kre  [36:72) Kim  [72:108) Qre  [108:144) Qim
// (Q weights folded: bank 0.025, joint 0.1, pos 0.5. Gate NOT folded.)

// ---------------- K1: phases + joint phases + pos phases + V ----------------
__global__ void k_phases(const float* __restrict__ x, const float* __restrict__ kp,
                         const float* __restrict__ qp, const float* __restrict__ vp,
                         const float* __restrict__ pos_freqs,
                         float* __restrict__ coef, float* __restrict__ V) {
    int bl = blockIdx.x;            // b*L + l
    int l  = bl & (LSEQ - 1);
    int t  = threadIdx.x;
    __shared__ float xs[DDIM];
    __shared__ float phi[32];
    xs[t] = x[bl * DDIM + t];
    __syncthreads();
    float* crow = coef + (size_t)bl * CSTR;
    if (t < 32) {
        const float* W = (t < 16) ? kp : qp;
        int j = t & 15;
        float acc = 0.f;
        #pragma unroll 8
        for (int i = 0; i < DDIM; ++i) acc += xs[i] * W[i * 16 + j];
        float ph = tanhf(acc) * PI_F;
        phi[t] = ph;
        float s, c; sincosf(ph, &s, &c);   // SIN FIRST
        if (t < 16) { crow[j] = c;               crow[36 + j] = s; }
        else        { crow[72 + j] = 0.025f * c; crow[108 + j] = 0.025f * s; }
    }
    __syncthreads();
    if (t < 8) {    // joint phases: sum over 4 sets at fixed pp
        int p = t & 3;
        const float* p4 = phi + ((t < 4) ? 0 : 16);
        float sum = p4[p] + p4[4 + p] + p4[8 + p] + p4[12 + p];
        float s, c; sincosf(sum, &s, &c);
        if (t < 4) { crow[16 + p] = c;          crow[52 + p] = s; }
        else       { crow[88 + p] = 0.1f * c;   crow[124 + p] = 0.1f * s; }
    }
    if (t >= 32 && t < 48) {  // positional phases (key AND weighted query copies)
        int pl = t - 32;
        float a = (((float)l * pos_freqs[pl]) * 2.0f) * PI_F;
        float s, c; sincosf(a, &s, &c);
        crow[20 + pl] = c;          crow[56 + pl] = s;
        crow[92 + pl] = 0.5f * c;   crow[128 + pl] = 0.5f * s;
    }
    // V = x @ value_proj (one output column per thread)
    float acc = 0.f;
    #pragma unroll 8
    for (int i = 0; i < DDIM; ++i) acc += xs[i] * vp[i * DDIM + t];
    V[(size_t)bl * DDIM + t] = acc;
}

// ---------------- K2a: per-chunk sums for running stats ----------------
__global__ void k_stats1(const float* __restrict__ x, float* __restrict__ Ssum,
                         float* __restrict__ Ssq) {
    int c = blockIdx.x, b = blockIdx.y, d = threadIdx.x;
    float s1 = 0.f, s2 = 0.f;
    for (int l = c * CHS; l < c * CHS + CHS; ++l) {
        float v = x[((size_t)(b * LSEQ + l)) * DDIM + d];
        s1 += v; s2 += v * v;
    }
    Ssum[(b * NCS + c) * DDIM + d] = s1;
    Ssq [(b * NCS + c) * DDIM + d] = s2;
}

// ---------------- K2b: running mean / std within chunk ----------------
__global__ void k_stats2(const float* __restrict__ x, const float* __restrict__ Ssum,
                         const float* __restrict__ Ssq, float* __restrict__ rmean,
                         float* __restrict__ rstd) {
    int c = blockIdx.x, b = blockIdx.y, d = threadIdx.x;
    float cs = 0.f, css = 0.f;
    for (int cc = 0; cc < c; ++cc) {
        cs  += Ssum[(b * NCS + cc) * DDIM + d];
        css += Ssq [(b * NCS + cc) * DDIM + d];
    }
    for (int l = c * CHS; l < c * CHS + CHS; ++l) {
        size_t idx = ((size_t)(b * LSEQ + l)) * DDIM + d;
        float v = x[idx];
        cs += v; css += v * v;
        float inv = 1.0f / (float)(l + 1);
        float m = cs * inv;
        float var = css * inv - m * m;
        rmean[idx] = m;
        rstd[idx] = sqrtf(fmaxf(var, 1e-8f));
    }
}

// ---------------- K3: LTM phases + persistent readout ----------------
__global__ void k_ltm(const float* __restrict__ x, const float* __restrict__ rmean,
                      const float* __restrict__ rstd, const float* __restrict__ lkp,
                      const float* __restrict__ bre, const float* __restrict__ bim,
                      float* __restrict__ pers) {
    int bl = blockIdx.x, t = threadIdx.x;
    __shared__ float ins[768];
    __shared__ float part[16][17];
    __shared__ float cs_[16], sn_[16];
    size_t row = (size_t)bl * DDIM;
    ins[t]        = x[row + t];
    ins[256 + t]  = rmean[row + t];
    ins[512 + t]  = rstd[row + t];
    __syncthreads();
    {   // parallel 768-dot: 16 outputs x 16 groups of 48
        int j = t & 15, g = t >> 4;
        int i0 = g * 48;
        float acc = 0.f;
        #pragma unroll
        for (int i = 0; i < 48; ++i) acc += ins[i0 + i] * lkp[(i0 + i) * 16 + j];
        part[g][j] = acc;
    }
    __syncthreads();
    if (t < 16) {
        float acc = 0.f;
        #pragma unroll
        for (int g = 0; g < 16; ++g) acc += part[g][t];
        float th = tanhf(acc) * PI_F;
        float s, c; sincosf(th, &s, &c);   // SIN FIRST
        cs_[t] = c; sn_[t] = s;
    }
    __syncthreads();
    float acc = 0.f;
    #pragma unroll
    for (int pl = 0; pl < 16; ++pl)
        acc += bre[pl * DDIM + t] * cs_[pl] + bim[pl * DDIM + t] * sn_[pl];
    pers[row + t] = acc;   // raw persistent sum; weighted 0.125 in k_scan
}

// ---------------- K4: write gate via parallel prefix scan ----------------
__global__ void k_gate(const float* __restrict__ coef, float* __restrict__ gate) {
    int b = blockIdx.x, t = threadIdx.x;
    __shared__ float sm[8][1056];   // 8 channels, padded
    __shared__ float part[8][33];
    for (int idx = t; idx < LSEQ * 8; idx += 256) {
        int l = idx >> 3, k = idx & 7;
        sm[k][F(l)] = coef[((size_t)(b * LSEQ + l)) * CSTR + ((k < 4) ? (16 + k) : (48 + k))];
    }
    __syncthreads();
    int g = t >> 5, r = t & 31;
    {   // local sums of 32-element segments
        float s = 0.f;
        int base = r * 33;    // F(r*32+i) = r*33+i
        #pragma unroll
        for (int i = 0; i < 32; ++i) s += sm[g][base + i];
        part[g][r] = s;
    }
    __syncthreads();
    if (r == 0) {   // exclusive scan of 32 partials per channel
        float run = 0.f;
        #pragma unroll
        for (int i = 0; i < 32; ++i) { float tmp = part[g][i]; part[g][i] = run; run += tmp; }
    }
    __syncthreads();
    {   // replay: replace with exclusive prefix
        float run = part[g][r];
        int base = r * 33;
        #pragma unroll
        for (int i = 0; i < 32; ++i) {
            float tmp = sm[g][base + i];
            sm[g][base + i] = run;
            run += tmp;
        }
    }
    __syncthreads();
    for (int l = t; l < LSEQ; l += 256) {
        float m = 0.f;
        int fl = F(l);
        #pragma unroll
        for (int p = 0; p < 4; ++p) {
            float ar = sm[p][fl], ai = sm[4 + p][fl];
            m += sqrtf(ar * ar + ai * ai);
        }
        m *= 0.25f;
        float nr = m / sqrtf(fmaxf((float)l, 1.0f));
        float sup = 0.5f * (1.0f - tanhf(5.0f * (nr - 0.3f)));
        gate[b * LSEQ + l] = 1.0f / (1.0f + expf(-5.0f * (sup - 0.5f)));
    }
}

// ---------------- K5a: per-chunk plane sums (uniform scalar coef reads) ----------------
__global__ void k_chunksum(const float* __restrict__ coef, const float* __restrict__ V,
                           const float* __restrict__ gate, float* __restrict__ S) {
    int c = blockIdx.x, b = blockIdx.y, d = threadIdx.x;
    const float* cr0 = coef + ((size_t)(b * LSEQ + c * CHUNK)) * CSTR;
    const float* gt  = gate + b * LSEQ + c * CHUNK;
    float vbuf[CHUNK];
    #pragma unroll
    for (int l = 0; l < CHUNK; ++l)
        vbuf[l] = V[((size_t)(b * LSEQ + c * CHUNK + l)) * DDIM + d];
    float sre[36], sim[36];
    #pragma unroll
    for (int i = 0; i < 36; ++i) { sre[i] = 0.f; sim[i] = 0.f; }
    #pragma unroll
    for (int l = 0; l < CHUNK; ++l) {
        const float* cr = cr0 + l * CSTR;   // block-uniform -> s_load
        float g = gt[l];                    // block-uniform
        float v = vbuf[l];
        float vg = v * g;
        #pragma unroll
        for (int q = 0; q < 9; ++q) {
            float val = (q <= 4) ? vg : v;   // planes 0-19 gated, 20-35 ungated
            #pragma unroll
            for (int j = 0; j < 4; ++j) {
                sre[4*q+j] += cr[4*q+j] * val;
                sim[4*q+j] += cr[36 + 4*q+j] * val;
            }
        }
    }
    size_t base = ((size_t)(b * NC + c) * 72) * DDIM + d;
    #pragma unroll
    for (int i = 0; i < 36; ++i) {
        S[base + (size_t)i * DDIM] = sre[i];
        S[base + (size_t)(36 + i) * DDIM] = sim[i];
    }
}

// ---------------- K5b: exclusive prefix over chunks (register-batched) ----------------
__global__ void k_prefix(float* __restrict__ S) {
    int q = blockIdx.x, b = blockIdx.y, d = threadIdx.x;
    float acc = 0.f;
    for (int batch = 0; batch < NC / 32; ++batch) {
        float r[32];
        #pragma unroll
        for (int i = 0; i < 32; ++i)
            r[i] = S[((size_t)(b * NC + batch * 32 + i) * 72 + q) * DDIM + d];
        #pragma unroll
        for (int i = 0; i < 32; ++i) { float tmp = r[i]; r[i] = acc; acc += tmp; }
        #pragma unroll
        for (int i = 0; i < 32; ++i)
            S[((size_t)(b * NC + batch * 32 + i) * 72 + q) * DDIM + d] = r[i];
    }
}

// ---------------- K5c: within-chunk scan + retrieval (+0.125*pers, in place) ----------------
__global__ void k_scan(const float* __restrict__ coef, const float* __restrict__ V,
                       const float* __restrict__ gate, const float* __restrict__ S,
                       float* __restrict__ tp) {
    int c = blockIdx.x, b = blockIdx.y, d = threadIdx.x;
    const float* cr0 = coef + ((size_t)(b * LSEQ + c * CHUNK)) * CSTR;
    const float* gt  = gate + b * LSEQ + c * CHUNK;
    float vbuf[CHUNK], tpb[CHUNK];
    #pragma unroll
    for (int l = 0; l < CHUNK; ++l) {
        size_t idx = ((size_t)(b * LSEQ + c * CHUNK + l)) * DDIM + d;
        vbuf[l] = V[idx];
        tpb[l]  = tp[idx];
    }
    float sre[36], sim[36];
    size_t base = ((size_t)(b * NC + c) * 72) * DDIM + d;
    #pragma unroll
    for (int i = 0; i < 36; ++i) {
        sre[i] = S[base + (size_t)i * DDIM];
        sim[i] = S[base + (size_t)(36 + i) * DDIM];
    }
    #pragma unroll
    for (int l = 0; l < CHUNK; ++l) {
        const float* cr = cr0 + l * CSTR;   // block-uniform -> s_load
        float g = gt[l];
        float v = vbuf[l];
        float vg = v * g;
        float rx = 0.f, ry = 0.f, rz = 0.f, rw = 0.f;
        #pragma unroll
        for (int q = 0; q < 9; ++q) {
            float val = (q <= 4) ? vg : v;
            sre[4*q+0] += cr[4*q+0] * val; rx += cr[72+4*q+0] * sre[4*q+0];
            sre[4*q+1] += cr[4*q+1] * val; ry += cr[72+4*q+1] * sre[4*q+1];
            sre[4*q+2] += cr[4*q+2] * val; rz += cr[72+4*q+2] * sre[4*q+2];
            sre[4*q+3] += cr[4*q+3] * val; rw += cr[72+4*q+3] * sre[4*q+3];
            sim[4*q+0] += cr[36+4*q+0] * val; rx += cr[108+4*q+0] * sim[4*q+0];
            sim[4*q+1] += cr[36+4*q+1] * val; ry += cr[108+4*q+1] * sim[4*q+1];
            sim[4*q+2] += cr[36+4*q+2] * val; rz += cr[108+4*q+2] * sim[4*q+2];
            sim[4*q+3] += cr[36+4*q+3] * val; rw += cr[108+4*q+3] * sim[4*q+3];
        }
        size_t oidx = ((size_t)(b * LSEQ + c * CHUNK + l)) * DDIM + d;
        tp[oidx] = ((rx + ry) + (rz + rw)) + 0.125f * tpb[l];  // tp aliases pers
    }
}

// ---------------- K6: epilogue: (total/norm) @ out_proj + x ----------------
__global__ void k_out(const float* __restrict__ x, const float* __restrict__ tp,
                      const float* __restrict__ op, float* __restrict__ out) {
    int bl = blockIdx.x, t = threadIdx.x;
    int l = bl & (LSEQ - 1);
    __shared__ __align__(16) float ts[DDIM];
    size_t row = (size_t)bl * DDIM;
    float invn = 1.0f / (2.0f * sqrtf((float)(l + 1)));
    ts[t] = tp[row + t] * invn;
    __syncthreads();
    float a0 = 0.f, a1 = 0.f, a2 = 0.f, a3 = 0.f;
    const float4* t4 = (const float4*)ts;
    #pragma unroll 4
    for (int i = 0; i < DDIM / 4; ++i) {
        float4 v = t4[i];
        a0 += v.x * op[(4*i+0) * DDIM + t];
        a1 += v.y * op[(4*i+1) * DDIM + t];
        a2 += v.z * op[(4*i+2) * DDIM + t];
        a3 += v.w * op[(4*i+3) * DDIM + t];
    }
    out[row + t] = x[row + t] + ((a0 + a1) + (a2 + a3));
}

extern "C" void kernel_launch(void* const* d_in, const int* in_sizes, int n_in,
                              void* d_out, int out_size, void* d_ws, size_t ws_size,
                              hipStream_t stream) {
    const float* x   = (const float*)d_in[0];
    const float* kp  = (const float*)d_in[1];
    const float* qp  = (const float*)d_in[2];
    const float* vp  = (const float*)d_in[3];
    const float* op  = (const float*)d_in[4];
    const float* lkp = (const float*)d_in[5];
    const float* pf  = (const float*)d_in[7];
    const float* bre = (const float*)d_in[10];
    const float* bim = (const float*)d_in[11];
    float* out = (float*)d_out;

    const int B = 2;
    float* w = (float*)d_ws;
    size_t off = 0;
    float* coef  = w + off; off += (size_t)B * LSEQ * CSTR;       // 294912
    float* V     = w + off; off += (size_t)B * LSEQ * DDIM;       // 524288
    float* pers  = w + off; off += (size_t)B * LSEQ * DDIM;       // aliased as tcp
    float* gate  = w + off; off += (size_t)B * LSEQ;
    float* Ssum  = w + off; off += (size_t)B * NCS * DDIM;
    float* Ssq   = w + off; off += (size_t)B * NCS * DDIM;
    // X region: rmean+rstd (dead after k_ltm) aliased with S (written by k_chunksum)
    float* rmean = w + off;
    float* rstd  = w + off + (size_t)B * LSEQ * DDIM;
    float* S     = w + off; off += (size_t)B * NC * 72 * DDIM;    // 2359296
    // total ~14.2 MB

    dim3 blk(DDIM);
    k_phases<<<dim3(B * LSEQ), blk, 0, stream>>>(x, kp, qp, vp, pf, coef, V);
    k_gate<<<dim3(B), blk, 0, stream>>>(coef, gate);
    k_stats1<<<dim3(NCS, B), blk, 0, stream>>>(x, Ssum, Ssq);
    k_stats2<<<dim3(NCS, B), blk, 0, stream>>>(x, Ssum, Ssq, rmean, rstd);
    k_ltm<<<dim3(B * LSEQ), blk, 0, stream>>>(x, rmean, rstd, lkp, bre, bim, pers);
    k_chunksum<<<dim3(NC, B), blk, 0, stream>>>(coef, V, gate, S);
    k_prefix<<<dim3(72, B), blk, 0, stream>>>(S);
    k_scan<<<dim3(NC, B), blk, 0, stream>>>(coef, V, gate, S, pers);
    k_out<<<dim3(B * LSEQ), blk, 0, stream>>>(x, pers, op, out);
}